// Round 1
// baseline (472.494 us; speedup 1.0000x reference)
//
#include <hip/hip_runtime.h>

typedef __attribute__((ext_vector_type(8))) short short8;
typedef __attribute__((ext_vector_type(4))) float floatx4;
typedef _Float16 half_t;
typedef __attribute__((ext_vector_type(2))) _Float16 half2_t;
typedef unsigned short u16;
typedef unsigned int u32;

#define D_DIM 512
#define PD_DIM 128

__device__ __forceinline__ u16 f2bf(float f){
  u32 u = __builtin_bit_cast(u32, f);
  u += 0x7fffu + ((u >> 16) & 1u);
  return (u16)(u >> 16);
}

__global__ void cvt_f32_bf16(const float* __restrict__ src, u16* __restrict__ dst, int n4){
  int i = blockIdx.x * blockDim.x + threadIdx.x;
  if (i < n4){
    float4 v = ((const float4*)src)[i];
    u16 o0 = f2bf(v.x), o1 = f2bf(v.y), o2 = f2bf(v.z), o3 = f2bf(v.w);
    u32 lo = (u32)o0 | ((u32)o1 << 16);
    u32 hi = (u32)o2 | ((u32)o3 << 16);
    ((u32*)dst)[i*2]   = lo;
    ((u32*)dst)[i*2+1] = hi;
  }
}

// C[m,n] = relu(sum_k A[m,k]*B[n,k]) -> bf16. A:8192x512, B:512x512, C:8192x512
__global__ __launch_bounds__(256) void gemm1_relu(const u16* __restrict__ A,
                                                  const u16* __restrict__ Bm,
                                                  u16* __restrict__ C){
  const int K = D_DIM;
  __shared__ u16 As[128*32];
  __shared__ u16 Bs[128*32];
  int tid = threadIdx.x;
  int m0 = blockIdx.x * 128, n0 = blockIdx.y * 128;
  int w = tid >> 6, lane = tid & 63;
  int wy = w >> 1, wx = w & 1;
  int mrow = lane & 15, kg = lane >> 4;
  floatx4 acc[4][4];
#pragma unroll
  for (int mt = 0; mt < 4; mt++)
#pragma unroll
    for (int nt = 0; nt < 4; nt++)
      acc[mt][nt] = (floatx4){0.f, 0.f, 0.f, 0.f};

  for (int k0 = 0; k0 < K; k0 += 32){
    __syncthreads();
#pragma unroll
    for (int i = 0; i < 2; i++){
      int c = tid + 256*i;           // 0..511 chunks of 8 halfs
      int row = c >> 2, koff = (c & 3) * 8;
      *(short8*)&As[row*32 + koff] = *(const short8*)&A[(size_t)(m0+row)*K + k0 + koff];
      *(short8*)&Bs[row*32 + koff] = *(const short8*)&Bm[(size_t)(n0+row)*K + k0 + koff];
    }
    __syncthreads();
    short8 af[4], bfr[4];
#pragma unroll
    for (int mt = 0; mt < 4; mt++) af[mt]  = *(const short8*)&As[(wy*64 + mt*16 + mrow)*32 + kg*8];
#pragma unroll
    for (int nt = 0; nt < 4; nt++) bfr[nt] = *(const short8*)&Bs[(wx*64 + nt*16 + mrow)*32 + kg*8];
#pragma unroll
    for (int mt = 0; mt < 4; mt++)
#pragma unroll
      for (int nt = 0; nt < 4; nt++)
        acc[mt][nt] = __builtin_amdgcn_mfma_f32_16x16x32_bf16(af[mt], bfr[nt], acc[mt][nt], 0, 0, 0);
  }
#pragma unroll
  for (int mt = 0; mt < 4; mt++){
    int rbase = m0 + wy*64 + mt*16 + kg*4;
#pragma unroll
    for (int nt = 0; nt < 4; nt++){
      int col = n0 + wx*64 + nt*16 + mrow;
#pragma unroll
      for (int i = 0; i < 4; i++){
        float v = acc[mt][nt][i];
        v = v > 0.f ? v : 0.f;
        C[(size_t)(rbase+i)*D_DIM + col] = f2bf(v);
      }
    }
  }
}

// Hn[m,:] = (A[m,:] @ Bm^T) / ||.||  -> f16. A:8192x512 bf16, Bm:128x512 bf16, Hn:8192x128 f16
__global__ __launch_bounds__(256) void gemm2_norm(const u16* __restrict__ A,
                                                  const u16* __restrict__ Bm,
                                                  half_t* __restrict__ Hn){
  const int K = D_DIM;
  __shared__ __align__(16) char smem[65536];
  u16* As = (u16*)smem;          // 128*32
  u16* Bs = As + 128*32;         // 128*32
  float* Cs = (float*)smem;      // 128*128 (reused after compute)
  int tid = threadIdx.x;
  int m0 = blockIdx.x * 128;
  int w = tid >> 6, lane = tid & 63;
  int wy = w >> 1, wx = w & 1;
  int mrow = lane & 15, kg = lane >> 4;
  floatx4 acc[4][4];
#pragma unroll
  for (int mt = 0; mt < 4; mt++)
#pragma unroll
    for (int nt = 0; nt < 4; nt++)
      acc[mt][nt] = (floatx4){0.f, 0.f, 0.f, 0.f};

  for (int k0 = 0; k0 < K; k0 += 32){
    __syncthreads();
#pragma unroll
    for (int i = 0; i < 2; i++){
      int c = tid + 256*i;
      int row = c >> 2, koff = (c & 3) * 8;
      *(short8*)&As[row*32 + koff] = *(const short8*)&A[(size_t)(m0+row)*K + k0 + koff];
      *(short8*)&Bs[row*32 + koff] = *(const short8*)&Bm[(size_t)row*K + k0 + koff];
    }
    __syncthreads();
    short8 af[4], bfr[4];
#pragma unroll
    for (int mt = 0; mt < 4; mt++) af[mt]  = *(const short8*)&As[(wy*64 + mt*16 + mrow)*32 + kg*8];
#pragma unroll
    for (int nt = 0; nt < 4; nt++) bfr[nt] = *(const short8*)&Bs[(wx*64 + nt*16 + mrow)*32 + kg*8];
#pragma unroll
    for (int mt = 0; mt < 4; mt++)
#pragma unroll
      for (int nt = 0; nt < 4; nt++)
        acc[mt][nt] = __builtin_amdgcn_mfma_f32_16x16x32_bf16(af[mt], bfr[nt], acc[mt][nt], 0, 0, 0);
  }
  __syncthreads();
#pragma unroll
  for (int mt = 0; mt < 4; mt++){
#pragma unroll
    for (int nt = 0; nt < 4; nt++){
      int cc = wx*64 + nt*16 + mrow;
#pragma unroll
      for (int i = 0; i < 4; i++){
        int r = wy*64 + mt*16 + kg*4 + i;
        Cs[r*128 + cc] = acc[mt][nt][i];
      }
    }
  }
  __syncthreads();
  int r = tid >> 1, hh = tid & 1;
  const float* rowp = Cs + r*128 + hh*64;
  float ssq = 0.f;
  for (int j = 0; j < 64; j++){
    float v = rowp[(j + tid) & 63];   // rotate to dodge bank conflicts
    ssq += v * v;
  }
  ssq += __shfl_xor(ssq, 1);
  float rn = rsqrtf(fmaxf(ssq, 1e-24f));
  half_t* orow = Hn + (size_t)(m0 + r)*PD_DIM + hh*64;
  for (int j = 0; j < 32; j++){
    int k2 = (j + r) & 31;
    float2 v = *(const float2*)(rowp + 2*k2);
    half2_t o;
    o.x = (half_t)(v.x * rn);
    o.y = (half_t)(v.y * rn);
    *(half2_t*)(orow + 2*k2) = o;
  }
}

__device__ __forceinline__ float dot2f(u32 a, u32 b, float c){
#if __has_builtin(__builtin_amdgcn_fdot2)
  return __builtin_amdgcn_fdot2(__builtin_bit_cast(half2_t, a),
                                __builtin_bit_cast(half2_t, b), c, false);
#else
  half2_t ha = __builtin_bit_cast(half2_t, a), hb = __builtin_bit_cast(half2_t, b);
  c += (float)ha.x * (float)hb.x;
  c += (float)ha.y * (float)hb.y;
  return c;
#endif
}

// one wave per pair; 4 groups of 16 lanes; 3 rounds x 4 dots cover 11 logits + dummy
__global__ __launch_bounds__(256) void pair_loss(const u32* __restrict__ hn2,
                                                 const int* __restrict__ anchors,
                                                 const int* __restrict__ positives,
                                                 const int* __restrict__ negs,
                                                 float* __restrict__ out,
                                                 int P, float scale){
  int l = threadIdx.x & 63;
  int g = l >> 4, t = l & 15;
  int wid = __builtin_amdgcn_readfirstlane(blockIdx.x*(blockDim.x >> 6) + (threadIdx.x >> 6));
  int nw = gridDim.x * (blockDim.x >> 6);
  float wsum = 0.f;
  for (int p = wid; p < P; p += nw){
    int a = anchors[p];
    const u32* arow = hn2 + (size_t)a * 64;
    u32 ad0 = arow[t], ad1 = arow[t+16], ad2 = arow[t+32], ad3 = arow[t+48];
    float lr[3];
#pragma unroll
    for (int r = 0; r < 3; r++){
      int j = r*4 + g;
      int o;
      if (j == 0)       o = positives[p];
      else if (j <= 10) o = negs[p*10 + j - 1];
      else              o = a;   // dummy slot 11, masked below
      const u32* orow = hn2 + (size_t)o * 64;
      float acc = 0.f;
      acc = dot2f(ad0, orow[t],    acc);
      acc = dot2f(ad1, orow[t+16], acc);
      acc = dot2f(ad2, orow[t+32], acc);
      acc = dot2f(ad3, orow[t+48], acc);
      acc += __shfl_xor(acc, 1);
      acc += __shfl_xor(acc, 2);
      acc += __shfl_xor(acc, 4);
      acc += __shfl_xor(acc, 8);
      lr[r] = acc * 2.0f;   // / TEMPERATURE
    }
    if (g == 3) lr[2] = -1e30f;
    float m = fmaxf(fmaxf(lr[0], lr[1]), lr[2]);
    m = fmaxf(m, __shfl_xor(m, 16));
    m = fmaxf(m, __shfl_xor(m, 32));
    float s = __expf(lr[0]-m) + __expf(lr[1]-m) + __expf(lr[2]-m);
    s += __shfl_xor(s, 16);
    s += __shfl_xor(s, 32);
    float pl = __shfl(lr[0], 0);
    if (l == 0) wsum += (m + __logf(s)) - pl;
  }
  if (l == 0) atomicAdd(out, wsum * scale);
}

extern "C" void kernel_launch(void* const* d_in, const int* in_sizes, int n_in,
                              void* d_out, int out_size, void* d_ws, size_t ws_size,
                              hipStream_t stream){
  const float* x  = (const float*)d_in[0];
  const float* w1 = (const float*)d_in[1];
  const float* w2 = (const float*)d_in[2];
  const int* anchors   = (const int*)d_in[4];
  const int* positives = (const int*)d_in[5];
  const int* negidx    = (const int*)d_in[6];
  int P = in_sizes[4];
  float* out = (float*)d_out;

  u16* x_b  = (u16*)d_ws;              // 8192*512
  u16* w1_b = x_b  + 4194304;          // 512*512
  u16* w2_b = w1_b + 262144;           // 128*512
  u16* h1_b = w2_b + 65536;            // 8192*512
  half_t* hn = (half_t*)(h1_b + 4194304); // 8192*128 f16

  cvt_f32_bf16<<<4096, 256, 0, stream>>>(x,  x_b,  4194304/4);
  cvt_f32_bf16<<<256,  256, 0, stream>>>(w1, w1_b, 262144/4);
  cvt_f32_bf16<<<64,   256, 0, stream>>>(w2, w2_b, 65536/4);
  gemm1_relu<<<dim3(64, 4), 256, 0, stream>>>(x_b, w1_b, h1_b);
  gemm2_norm<<<dim3(64), 256, 0, stream>>>(h1_b, w2_b, hn);
  hipMemsetAsync(out, 0, sizeof(float), stream);
  pair_loss<<<2048, 256, 0, stream>>>((const u32*)hn, anchors, positives, negidx,
                                      out, P, 1.0f/(float)P);
}